// Round 1
// baseline (489.950 us; speedup 1.0000x reference)
//
#include <hip/hip_runtime.h>
#include <hip/hip_bf16.h>
#include <stdint.h>

#define S_LEN 2048
#define NB    2
#define HQ    16
#define HKV   4
#define HD    128
#define QB    64   // q rows per block (4 waves x 16)
#define KVB   32   // kv rows per iteration

typedef __bf16 bf16_t;
typedef __attribute__((ext_vector_type(8))) __bf16 bf16x8;
typedef __attribute__((ext_vector_type(4))) float  f32x4;

// ---------------- RoPE table: tab[s*64+i] = (cos, sin) of s * 10000^(-i/64) ----
__global__ void rope_table_kernel(float2* __restrict__ tab) {
  int idx = blockIdx.x * blockDim.x + threadIdx.x;
  if (idx >= S_LEN * 64) return;
  int t = idx >> 6;
  int i = idx & 63;
  float inv = exp2f(-(float)i * (13.287712379549449f / 64.0f)); // 10000^(-i/64)
  float ang = (float)t * inv;
  tab[idx] = make_float2(cosf(ang), sinf(ang));
}

// ---------------- Q/K: L2-normalize (eps clamp) + RoPE + bf16, head-major -----
// one wave per row of 128; Q gets 1/sqrt(128) folded in.
__global__ void qk_preproc_kernel(const float* __restrict__ xq,
                                  const float* __restrict__ xk,
                                  const float2* __restrict__ tab,
                                  bf16_t* __restrict__ Qr,
                                  bf16_t* __restrict__ Kr) {
  int wid  = (blockIdx.x * blockDim.x + threadIdx.x) >> 6;
  int lane = threadIdx.x & 63;
  const int per_bs = HQ + HKV;
  int b   = wid / (S_LEN * per_bs);
  int rem = wid - b * (S_LEN * per_bs);
  int s   = rem / per_bs;
  int hh  = rem - s * per_bs;
  const float* src;
  bf16_t* dst;
  float scale;
  if (hh < HQ) {
    src = xq + ((size_t)(b * S_LEN + s) * (HQ * HD)) + hh * HD;
    dst = Qr + (((size_t)(b * HQ + hh) * S_LEN + s) * HD);
    scale = 0.08838834764831845f;   // 1/sqrt(128) folded into Q
  } else {
    int h = hh - HQ;
    src = xk + ((size_t)(b * S_LEN + s) * (HKV * HD)) + h * HD;
    dst = Kr + (((size_t)(b * HKV + h) * S_LEN + s) * HD);
    scale = 1.0f;
  }
  float x1 = src[lane];
  float x2 = src[64 + lane];
  float ss = x1 * x1 + x2 * x2;
  #pragma unroll
  for (int m = 1; m < 64; m <<= 1) ss += __shfl_xor(ss, m, 64);
  float rinv = scale / fmaxf(sqrtf(ss), 1e-6f);
  float2 cs = tab[s * 64 + lane];
  float q1 = x1 * rinv, q2 = x2 * rinv;
  dst[lane]      = (bf16_t)(q1 * cs.x + q2 * cs.y);   // y1 = x1*c + x2*s
  dst[64 + lane] = (bf16_t)(q2 * cs.x - q1 * cs.y);   // y2 = -x1*s + x2*c
}

// ---------------- V: bf16 cast + transpose to Vt[b][h][d][s] ------------------
__global__ void v_preproc_kernel(const float* __restrict__ xv,
                                 bf16_t* __restrict__ Vt) {
  int bhd = blockIdx.x;              // (b*HKV + h)*HD + d
  int d  = bhd % HD;
  int bh = bhd / HD;
  int h  = bh % HKV;
  int b  = bh / HKV;
  const float* src = xv + (size_t)b * S_LEN * (HKV * HD) + h * HD + d;
  bf16_t* dst = Vt + (size_t)bhd * S_LEN;
  for (int s = threadIdx.x; s < S_LEN; s += blockDim.x)
    dst[s] = (bf16_t)src[(size_t)s * (HKV * HD)];
}

// ---------------- Flash attention: 4 independent waves, 16 q-rows each --------
__global__ void attn_kernel(const bf16_t* __restrict__ Qr,
                            const bf16_t* __restrict__ Kr,
                            const bf16_t* __restrict__ Vt,
                            float* __restrict__ out) {
  // padded stride 40 shorts (80B): row-stride 20 words -> 2-way bank alias (free)
  __shared__ unsigned short p_lds[4][16][40];

  const int w    = threadIdx.x >> 6;
  const int lane = threadIdx.x & 63;
  const int g    = lane >> 4;      // 16-lane group 0..3
  const int c    = lane & 15;      // col-in-tile / row-for-A
  const int bh   = blockIdx.y;
  const int b    = bh >> 4;
  const int h    = bh & 15;
  const int kvh  = h >> 2;         // GQA: repeat(k,4) -> q head h uses kv head h/4
  const int qw   = blockIdx.x * QB + w * 16;   // this wave's 16 q rows

  const bf16_t* Qbase = Qr + (size_t)(b * HQ  + h  ) * S_LEN * HD;
  const bf16_t* Kbase = Kr + (size_t)(b * HKV + kvh) * S_LEN * HD;
  const bf16_t* Vbase = Vt + (size_t)(b * HKV + kvh) * HD * S_LEN;

  // Q A-fragments: lane holds Q[qw + c][kk*32 + g*8 .. +7]
  bf16x8 qf[4];
  #pragma unroll
  for (int kk = 0; kk < 4; ++kk)
    qf[kk] = *reinterpret_cast<const bf16x8*>(Qbase + (size_t)(qw + c) * HD + kk * 32 + g * 8);

  f32x4 acc[8];
  #pragma unroll
  for (int i = 0; i < 8; ++i) acc[i] = (f32x4){0.f, 0.f, 0.f, 0.f};
  float mrun[4], lrun[4];
  #pragma unroll
  for (int r = 0; r < 4; ++r) { mrun[r] = -3.0e38f; lrun[r] = 0.f; }

  const int kv_end = qw + 16;      // causal bound for this wave

  for (int kb = 0; kb < kv_end; kb += KVB) {
    // ---- S = Q K^T for two 16-wide kv tiles
    f32x4 s0 = (f32x4){0.f, 0.f, 0.f, 0.f};
    f32x4 s1 = (f32x4){0.f, 0.f, 0.f, 0.f};
    #pragma unroll
    for (int kk = 0; kk < 4; ++kk) {
      bf16x8 k0 = *reinterpret_cast<const bf16x8*>(Kbase + (size_t)(kb + c) * HD + kk * 32 + g * 8);
      s0 = __builtin_amdgcn_mfma_f32_16x16x32_bf16(qf[kk], k0, s0, 0, 0, 0);
    }
    #pragma unroll
    for (int kk = 0; kk < 4; ++kk) {
      bf16x8 k1 = *reinterpret_cast<const bf16x8*>(Kbase + (size_t)(kb + 16 + c) * HD + kk * 32 + g * 8);
      s1 = __builtin_amdgcn_mfma_f32_16x16x32_bf16(qf[kk], k1, s1, 0, 0, 0);
    }

    // ---- online softmax per q-row (row r lives on 16 lanes of group g)
    const int qrow_base = qw + g * 4;
    #pragma unroll
    for (int r = 0; r < 4; ++r) {
      const int qrow = qrow_base + r;
      float v0 = s0[r], v1 = s1[r];
      if (kb + c > qrow)      v0 = -3.0e38f;   // causal mask
      if (kb + 16 + c > qrow) v1 = -3.0e38f;
      float t = fmaxf(v0, v1);
      t = fmaxf(t, __shfl_xor(t, 1, 64));
      t = fmaxf(t, __shfl_xor(t, 2, 64));
      t = fmaxf(t, __shfl_xor(t, 4, 64));
      t = fmaxf(t, __shfl_xor(t, 8, 64));
      const float mn   = fmaxf(mrun[r], t);
      const float resc = __expf(mrun[r] - mn);
      const float p0   = __expf(v0 - mn);
      const float p1   = __expf(v1 - mn);
      float ps = p0 + p1;
      ps += __shfl_xor(ps, 1, 64);
      ps += __shfl_xor(ps, 2, 64);
      ps += __shfl_xor(ps, 4, 64);
      ps += __shfl_xor(ps, 8, 64);
      lrun[r] = lrun[r] * resc + ps;
      mrun[r] = mn;
      #pragma unroll
      for (int dt = 0; dt < 8; ++dt) acc[dt][r] *= resc;
      p_lds[w][g * 4 + r][c]      = __builtin_bit_cast(unsigned short, (bf16_t)p0);
      p_lds[w][g * 4 + r][16 + c] = __builtin_bit_cast(unsigned short, (bf16_t)p1);
    }

    // ---- PV: A = P (via LDS transpose), B = Vt rows (contiguous over s)
    bf16x8 pf = *reinterpret_cast<const bf16x8*>(&p_lds[w][c][g * 8]);
    #pragma unroll
    for (int dt = 0; dt < 8; ++dt) {
      bf16x8 vf = *reinterpret_cast<const bf16x8*>(Vbase + (size_t)(dt * 16 + c) * S_LEN + kb + g * 8);
      acc[dt] = __builtin_amdgcn_mfma_f32_16x16x32_bf16(pf, vf, acc[dt], 0, 0, 0);
    }
  }

  // ---- epilogue: out[b][q][h*128 + d] = acc / l
  #pragma unroll
  for (int r = 0; r < 4; ++r) {
    const float inv = 1.0f / lrun[r];
    const int qrow  = qw + g * 4 + r;
    float* orow = out + ((size_t)(b * S_LEN + qrow) * (HQ * HD)) + h * HD;
    #pragma unroll
    for (int dt = 0; dt < 8; ++dt)
      orow[dt * 16 + c] = acc[dt][r] * inv;
  }
}

extern "C" void kernel_launch(void* const* d_in, const int* in_sizes, int n_in,
                              void* d_out, int out_size, void* d_ws, size_t ws_size,
                              hipStream_t stream) {
  const float* xq = (const float*)d_in[0];
  const float* xk = (const float*)d_in[1];
  const float* xv = (const float*)d_in[2];
  float* out = (float*)d_out;

  char* ws = (char*)d_ws;
  float2* tab = (float2*)ws;
  size_t off = (size_t)S_LEN * 64 * sizeof(float2);                  // 1 MB
  bf16_t* Qr = (bf16_t*)(ws + off); off += (size_t)NB * HQ  * S_LEN * HD * sizeof(bf16_t); // 16 MB
  bf16_t* Kr = (bf16_t*)(ws + off); off += (size_t)NB * HKV * S_LEN * HD * sizeof(bf16_t); //  4 MB
  bf16_t* Vt = (bf16_t*)(ws + off);                                                        //  4 MB

  rope_table_kernel<<<(S_LEN * 64 + 255) / 256, 256, 0, stream>>>(tab);

  const int nrow = NB * S_LEN * (HQ + HKV);        // 81920 waves
  qk_preproc_kernel<<<nrow / 4, 256, 0, stream>>>(xq, xk, tab, Qr, Kr);

  v_preproc_kernel<<<NB * HKV * HD, 256, 0, stream>>>(xv, Vt);

  dim3 grid(S_LEN / QB, NB * HQ);
  attn_kernel<<<grid, 256, 0, stream>>>(Qr, Kr, Vt, out);
}

// Round 2
// 200.786 us; speedup vs baseline: 2.4402x; 2.4402x over previous
//
#include <hip/hip_runtime.h>
#include <hip/hip_bf16.h>
#include <stdint.h>

#define S_LEN 2048
#define NB    2
#define HQ    16
#define HKV   4
#define HD    128
#define QB    64   // q rows per block (4 waves x 16)
#define KVB   64   // kv rows per staged tile

typedef __bf16 bf16_t;
typedef __attribute__((ext_vector_type(8))) __bf16 bf16x8;
typedef __attribute__((ext_vector_type(4))) float  f32x4;

__device__ __forceinline__ void gload_lds16(const bf16_t* g, bf16_t* l) {
  __builtin_amdgcn_global_load_lds(
      (const __attribute__((address_space(1))) unsigned int*)g,
      (__attribute__((address_space(3))) unsigned int*)l, 16, 0, 0);
}

// ---------------- RoPE table: tab[s*64+i] = (cos, sin) of s * 10000^(-i/64) ----
__global__ void rope_table_kernel(float2* __restrict__ tab) {
  int idx = blockIdx.x * blockDim.x + threadIdx.x;
  if (idx >= S_LEN * 64) return;
  int t = idx >> 6;
  int i = idx & 63;
  float inv = exp2f(-(float)i * (13.287712379549449f / 64.0f)); // 10000^(-i/64)
  float ang = (float)t * inv;
  tab[idx] = make_float2(cosf(ang), sinf(ang));
}

// ---------------- Q/K: L2-normalize (eps clamp) + RoPE + bf16, head-major -----
__global__ void qk_preproc_kernel(const float* __restrict__ xq,
                                  const float* __restrict__ xk,
                                  const float2* __restrict__ tab,
                                  bf16_t* __restrict__ Qr,
                                  bf16_t* __restrict__ Kr) {
  int wid  = (blockIdx.x * blockDim.x + threadIdx.x) >> 6;
  int lane = threadIdx.x & 63;
  const int per_bs = HQ + HKV;
  int b   = wid / (S_LEN * per_bs);
  int rem = wid - b * (S_LEN * per_bs);
  int s   = rem / per_bs;
  int hh  = rem - s * per_bs;
  const float* src;
  bf16_t* dst;
  float scale;
  if (hh < HQ) {
    src = xq + ((size_t)(b * S_LEN + s) * (HQ * HD)) + hh * HD;
    dst = Qr + (((size_t)(b * HQ + hh) * S_LEN + s) * HD);
    scale = 0.08838834764831845f;   // 1/sqrt(128) folded into Q
  } else {
    int h = hh - HQ;
    src = xk + ((size_t)(b * S_LEN + s) * (HKV * HD)) + h * HD;
    dst = Kr + (((size_t)(b * HKV + h) * S_LEN + s) * HD);
    scale = 1.0f;
  }
  float x1 = src[lane];
  float x2 = src[64 + lane];
  float ss = x1 * x1 + x2 * x2;
  #pragma unroll
  for (int m = 1; m < 64; m <<= 1) ss += __shfl_xor(ss, m, 64);
  float rinv = scale / fmaxf(sqrtf(ss), 1e-6f);
  float2 cs = tab[s * 64 + lane];
  float q1 = x1 * rinv, q2 = x2 * rinv;
  dst[lane]      = (bf16_t)(q1 * cs.x + q2 * cs.y);
  dst[64 + lane] = (bf16_t)(q2 * cs.x - q1 * cs.y);
}

// ---------------- V: bf16 cast + transpose into contiguous 16KB panels --------
// Vtt[b][kvh][t][d][64]: panel t = V^T tile for kv rows [t*64, t*64+64)
__global__ void v_preproc_kernel(const float* __restrict__ xv,
                                 bf16_t* __restrict__ Vtt) {
  int bhd = blockIdx.x;              // (b*HKV + h)*HD + d
  int d  = bhd % HD;
  int bh = bhd / HD;
  int h  = bh % HKV;
  int b  = bh / HKV;
  const float* src = xv + (size_t)b * S_LEN * (HKV * HD) + h * HD + d;
  bf16_t* dstbase = Vtt + (size_t)bh * 32 * (HD * KVB);
  for (int s = threadIdx.x; s < S_LEN; s += blockDim.x)
    dstbase[(size_t)(s >> 6) * (HD * KVB) + d * KVB + (s & 63)] =
        (bf16_t)src[(size_t)s * (HKV * HD)];
}

// ---------------- Flash attention: LDS-staged, double-buffered, swizzled ------
__global__ __launch_bounds__(256) void attn_kernel(const bf16_t* __restrict__ Qr,
                            const bf16_t* __restrict__ Kr,
                            const bf16_t* __restrict__ Vtt,
                            float* __restrict__ out) {
  __shared__ bf16_t Kbuf[2][KVB * HD];          // 16 KB x 2, rows=s, swizzled
  __shared__ bf16_t Vbuf[2][HD * KVB];          // 16 KB x 2, rows=d, swizzled
  __shared__ unsigned short p_lds[4][16][72];   // per-wave P transpose, stride 72

  const int w    = threadIdx.x >> 6;
  const int lane = threadIdx.x & 63;
  const int g    = lane >> 4;
  const int c    = lane & 15;
  const int bh   = blockIdx.y;
  const int b    = bh >> 4;
  const int h    = bh & 15;
  const int kvh  = h >> 2;
  const int blk  = (int)gridDim.x - 1 - (int)blockIdx.x;  // heavy blocks first
  const int qw   = blk * QB + w * 16;
  const int nt   = blk + 1;                               // KVB=64 tiles to do

  const bf16_t* Qbase = Qr  + (size_t)(b * HQ  + h  ) * S_LEN * HD;
  const bf16_t* Kbase = Kr  + (size_t)(b * HKV + kvh) * S_LEN * HD;
  const bf16_t* Vbase = Vtt + (size_t)(b * HKV + kvh) * 32 * (HD * KVB);

  // per-lane pre-swizzled staging source offsets (elements); LDS dest is linear
  int koff[4], voff[4];
  #pragma unroll
  for (int i = 0; i < 4; ++i) {
    int n = w * 256 + i * 64 + lane;               // 16B-chunk index in tile
    koff[i] = ((n & ~15) | ((n & 15) ^ ((n >> 4) & 7))) * 8;  // K: 16 chunks/row
    voff[i] = ((n & ~7)  | ((n & 7)  ^ ((n >> 3) & 7))) * 8;  // V: 8 chunks/row
  }

  // Q fragments: lane holds Q[qw + c][kk*32 + g*8 .. +7]
  bf16x8 qf[4];
  #pragma unroll
  for (int kk = 0; kk < 4; ++kk)
    qf[kk] = *reinterpret_cast<const bf16x8*>(Qbase + (size_t)(qw + c) * HD + kk * 32 + g * 8);

  f32x4 acc[8];
  #pragma unroll
  for (int i = 0; i < 8; ++i) acc[i] = (f32x4){0.f, 0.f, 0.f, 0.f};
  float mrun[4], lrun[4];
  #pragma unroll
  for (int r = 0; r < 4; ++r) { mrun[r] = -3.0e38f; lrun[r] = 0.f; }

  // prologue: stage tile 0 into buffer 0
  #pragma unroll
  for (int i = 0; i < 4; ++i) {
    gload_lds16(Kbase + koff[i], &Kbuf[0][(w * 256 + i * 64) * 8]);
    gload_lds16(Vbase + voff[i], &Vbuf[0][(w * 256 + i * 64) * 8]);
  }
  __syncthreads();

  for (int t = 0; t < nt; ++t) {
    const int pb = t & 1;
    if (t + 1 < nt) {     // issue next tile's async loads into the other buffer
      const bf16_t* kg = Kbase + (size_t)(t + 1) * (KVB * HD);
      const bf16_t* vg = Vbase + (size_t)(t + 1) * (HD * KVB);
      #pragma unroll
      for (int i = 0; i < 4; ++i) {
        gload_lds16(kg + koff[i], &Kbuf[pb ^ 1][(w * 256 + i * 64) * 8]);
        gload_lds16(vg + voff[i], &Vbuf[pb ^ 1][(w * 256 + i * 64) * 8]);
      }
    }

    // ---- S = Q K^T on staged tile (4 x 16-wide kv subtiles)
    f32x4 s[4];
    #pragma unroll
    for (int j = 0; j < 4; ++j) {
      s[j] = (f32x4){0.f, 0.f, 0.f, 0.f};
      #pragma unroll
      for (int kk = 0; kk < 4; ++kk) {
        const bf16x8 kf = *reinterpret_cast<const bf16x8*>(
            &Kbuf[pb][(j * 16 + c) * HD + (((kk * 4 + g) ^ (c & 7)) * 8)]);
        s[j] = __builtin_amdgcn_mfma_f32_16x16x32_bf16(qf[kk], kf, s[j], 0, 0, 0);
      }
    }

    // ---- online softmax (row r of group g); mask only in the tail tile
    const bool tail = (t == nt - 1);
    #pragma unroll
    for (int r = 0; r < 4; ++r) {
      const int lrow = w * 16 + g * 4 + r;   // q row relative to tail tile base
      float v0 = s[0][r], v1 = s[1][r], v2 = s[2][r], v3 = s[3][r];
      if (tail) {
        if ( 0 + c > lrow) v0 = -3.0e38f;
        if (16 + c > lrow) v1 = -3.0e38f;
        if (32 + c > lrow) v2 = -3.0e38f;
        if (48 + c > lrow) v3 = -3.0e38f;
      }
      float mx = fmaxf(fmaxf(v0, v1), fmaxf(v2, v3));
      mx = fmaxf(mx, __shfl_xor(mx, 1, 64));
      mx = fmaxf(mx, __shfl_xor(mx, 2, 64));
      mx = fmaxf(mx, __shfl_xor(mx, 4, 64));
      mx = fmaxf(mx, __shfl_xor(mx, 8, 64));
      const float mn   = fmaxf(mrun[r], mx);
      const float resc = __expf(mrun[r] - mn);
      const float p0 = __expf(v0 - mn);
      const float p1 = __expf(v1 - mn);
      const float p2 = __expf(v2 - mn);
      const float p3 = __expf(v3 - mn);
      float ps = (p0 + p1) + (p2 + p3);
      ps += __shfl_xor(ps, 1, 64);
      ps += __shfl_xor(ps, 2, 64);
      ps += __shfl_xor(ps, 4, 64);
      ps += __shfl_xor(ps, 8, 64);
      lrun[r] = lrun[r] * resc + ps;
      mrun[r] = mn;
      #pragma unroll
      for (int dt = 0; dt < 8; ++dt) acc[dt][r] *= resc;
      p_lds[w][g * 4 + r][ 0 + c] = __builtin_bit_cast(unsigned short, (bf16_t)p0);
      p_lds[w][g * 4 + r][16 + c] = __builtin_bit_cast(unsigned short, (bf16_t)p1);
      p_lds[w][g * 4 + r][32 + c] = __builtin_bit_cast(unsigned short, (bf16_t)p2);
      p_lds[w][g * 4 + r][48 + c] = __builtin_bit_cast(unsigned short, (bf16_t)p3);
    }

    // ---- PV: A = P (LDS transpose), B = V^T rows from swizzled Vbuf
    #pragma unroll
    for (int ks = 0; ks < 2; ++ks) {
      const bf16x8 pf = *reinterpret_cast<const bf16x8*>(&p_lds[w][c][ks * 32 + g * 8]);
      #pragma unroll
      for (int dt = 0; dt < 8; ++dt) {
        const bf16x8 vf = *reinterpret_cast<const bf16x8*>(
            &Vbuf[pb][(dt * 16 + c) * KVB + (((ks * 4 + g) ^ (c & 7)) * 8)]);
        acc[dt] = __builtin_amdgcn_mfma_f32_16x16x32_bf16(pf, vf, acc[dt], 0, 0, 0);
      }
    }

    __syncthreads();   // staged loads drained (vmcnt) + all reads of pb done
  }

  // ---- epilogue
  #pragma unroll
  for (int r = 0; r < 4; ++r) {
    const float inv = 1.0f / lrun[r];
    const int qrow  = qw + g * 4 + r;
    float* orow = out + ((size_t)(b * S_LEN + qrow) * (HQ * HD)) + h * HD;
    #pragma unroll
    for (int dt = 0; dt < 8; ++dt)
      orow[dt * 16 + c] = acc[dt][r] * inv;
  }
}

extern "C" void kernel_launch(void* const* d_in, const int* in_sizes, int n_in,
                              void* d_out, int out_size, void* d_ws, size_t ws_size,
                              hipStream_t stream) {
  const float* xq = (const float*)d_in[0];
  const float* xk = (const float*)d_in[1];
  const float* xv = (const float*)d_in[2];
  float* out = (float*)d_out;

  char* ws = (char*)d_ws;
  float2* tab = (float2*)ws;
  size_t off = (size_t)S_LEN * 64 * sizeof(float2);
  bf16_t* Qr  = (bf16_t*)(ws + off); off += (size_t)NB * HQ  * S_LEN * HD * sizeof(bf16_t);
  bf16_t* Kr  = (bf16_t*)(ws + off); off += (size_t)NB * HKV * S_LEN * HD * sizeof(bf16_t);
  bf16_t* Vtt = (bf16_t*)(ws + off);

  rope_table_kernel<<<(S_LEN * 64 + 255) / 256, 256, 0, stream>>>(tab);

  const int nrow = NB * S_LEN * (HQ + HKV);
  qk_preproc_kernel<<<nrow / 4, 256, 0, stream>>>(xq, xk, tab, Qr, Kr);

  v_preproc_kernel<<<NB * HKV * HD, 256, 0, stream>>>(xv, Vtt);

  dim3 grid(S_LEN / QB, NB * HQ);
  attn_kernel<<<grid, 256, 0, stream>>>(Qr, Kr, Vtt, out);
}

// Round 4
// 185.508 us; speedup vs baseline: 2.6411x; 1.0824x over previous
//
#include <hip/hip_runtime.h>
#include <hip/hip_bf16.h>
#include <stdint.h>

#define S_LEN 2048
#define NB    2
#define HQ    16
#define HKV   4
#define HD    128
#define KVB   64   // kv rows per staged tile
#define QBW   32   // q rows per wave
#define QBB   128  // q rows per block (4 waves)

typedef __bf16 bf16_t;
typedef __attribute__((ext_vector_type(8)))  __bf16 bf16x8;
typedef __attribute__((ext_vector_type(4)))  float  f32x4;
typedef __attribute__((ext_vector_type(16))) float  f32x16;
typedef __attribute__((ext_vector_type(4)))  unsigned int u32x4;

__device__ __forceinline__ void gload_lds16(const bf16_t* g, bf16_t* l) {
  __builtin_amdgcn_global_load_lds(
      (const __attribute__((address_space(1))) unsigned int*)g,
      (__attribute__((address_space(3))) unsigned int*)l, 16, 0, 0);
}
__device__ __forceinline__ uint32_t pack2(float lo, float hi) {
  uint32_t a = (uint32_t)__builtin_bit_cast(unsigned short, (bf16_t)lo);
  uint32_t b = (uint32_t)__builtin_bit_cast(unsigned short, (bf16_t)hi);
  return a | (b << 16);
}

// ---------------- RoPE table ---------------------------------------------------
__global__ void rope_table_kernel(float2* __restrict__ tab) {
  int idx = blockIdx.x * blockDim.x + threadIdx.x;
  if (idx >= S_LEN * 64) return;
  int t = idx >> 6;
  int i = idx & 63;
  float inv = exp2f(-(float)i * (13.287712379549449f / 64.0f)); // 10000^(-i/64)
  float ang = (float)t * inv;
  tab[idx] = make_float2(cosf(ang), sinf(ang));
}

// ---------------- Q/K: L2-norm + RoPE + bf16; Q gets scale*log2e folded in ----
__global__ void qk_preproc_kernel(const float* __restrict__ xq,
                                  const float* __restrict__ xk,
                                  const float2* __restrict__ tab,
                                  bf16_t* __restrict__ Qr,
                                  bf16_t* __restrict__ Kr) {
  int wid  = (blockIdx.x * blockDim.x + threadIdx.x) >> 6;
  int lane = threadIdx.x & 63;
  const int per_bs = HQ + HKV;
  int b   = wid / (S_LEN * per_bs);
  int rem = wid - b * (S_LEN * per_bs);
  int s   = rem / per_bs;
  int hh  = rem - s * per_bs;
  const float* src;
  bf16_t* dst;
  float scale;
  if (hh < HQ) {
    src = xq + ((size_t)(b * S_LEN + s) * (HQ * HD)) + hh * HD;
    dst = Qr + (((size_t)(b * HQ + hh) * S_LEN + s) * HD);
    scale = 0.08838834764831845f * 1.4426950408889634f;  // (1/sqrt128)*log2e
  } else {
    int h = hh - HQ;
    src = xk + ((size_t)(b * S_LEN + s) * (HKV * HD)) + h * HD;
    dst = Kr + (((size_t)(b * HKV + h) * S_LEN + s) * HD);
    scale = 1.0f;
  }
  float x1 = src[lane];
  float x2 = src[64 + lane];
  float ss = x1 * x1 + x2 * x2;
  #pragma unroll
  for (int m = 1; m < 64; m <<= 1) ss += __shfl_xor(ss, m, 64);
  float rinv = scale / fmaxf(sqrtf(ss), 1e-6f);
  float2 cs = tab[s * 64 + lane];
  float q1 = x1 * rinv, q2 = x2 * rinv;
  dst[lane]      = (bf16_t)(q1 * cs.x + q2 * cs.y);
  dst[64 + lane] = (bf16_t)(q2 * cs.x - q1 * cs.y);
}

// ---------------- V: coalesced read, bf16, transpose to [bh][t][d][64] panels --
__global__ void v_preproc_kernel(const float* __restrict__ xv,
                                 bf16_t* __restrict__ Vtt) {
  int bh = blockIdx.x >> 5;          // b*HKV + h
  int sc = blockIdx.x & 31;          // 64-row s chunk
  int b = bh >> 2, hh = bh & 3;
  const int d  = threadIdx.x & 127;
  const int s2 = threadIdx.x >> 7;   // 0..1
  const float* src = xv + (size_t)b * S_LEN * (HKV * HD) + hh * HD;
  bf16_t* dstb = Vtt + (size_t)bh * 32 * (HD * KVB);
  for (int it = 0; it < 32; ++it) {
    int s = sc * 64 + it * 2 + s2;
    float v = src[(size_t)s * (HKV * HD) + d];
    dstb[(size_t)(s >> 6) * (HD * KVB) + d * KVB + (s & 63)] = (bf16_t)v;
  }
}

// ---------------- Flash attention: swapped-QK^T 32x32, in-register softmax -----
__global__ __launch_bounds__(256) void attn_kernel(const bf16_t* __restrict__ Qr,
                                                   const bf16_t* __restrict__ Kr,
                                                   const bf16_t* __restrict__ Vtt,
                                                   float* __restrict__ out) {
  __shared__ bf16_t Kbuf[2][KVB * HD];   // 16 KB x2, row=kv(64) x d(128), swizzled
  __shared__ bf16_t Vbuf[2][HD * KVB];   // 16 KB x2, row=d(128) x kv(64), swizzled

  const int w    = threadIdx.x >> 6;
  const int lane = threadIdx.x & 63;
  const int r0   = lane & 31;            // q col / mfma row
  const int hi   = lane >> 5;
  const int r7   = lane & 7;
  const int y    = blockIdx.y;
  const int b    = y >> 4;
  const int h    = y & 15;
  const int kvh  = h >> 2;
  // heavy-first with pairing flip so paired dispatches get complementary work
  const int blk  = (y & 16) ? (int)blockIdx.x : (int)gridDim.x - 1 - (int)blockIdx.x;
  const int qb   = blk * QBB;
  const int qw0  = qb + w * QBW;
  const int qrow = qw0 + r0;
  const int qmax = qw0 + 31;
  const int nt   = (qb + QBB) >> 6;      // tiles of 64 kv

  const bf16_t* Qbase = Qr  + (size_t)(b * HQ  + h  ) * S_LEN * HD;
  const bf16_t* Kbase = Kr  + (size_t)(b * HKV + kvh) * S_LEN * HD;
  const bf16_t* Vbase = Vtt + (size_t)(b * HKV + kvh) * 32 * (HD * KVB);

  // pre-swizzled staging source offsets (elements); LDS dest linear (rule 21)
  int koff[4], voff[4];
  #pragma unroll
  for (int i = 0; i < 4; ++i) {
    int n = w * 256 + i * 64 + lane;
    koff[i] = ((n & ~15) | ((n & 15) ^ ((n >> 4) & 7))) * 8;  // K: 16 chunks/row
    voff[i] = ((n & ~7)  | ((n & 7)  ^ ((n >> 3) & 7))) * 8;  // V: 8 chunks/row
  }

  // Q fragments (B-operand of swapped QK^T): lane holds Q[qrow][kk*16+hi*8 ..+8)
  bf16x8 qf[8];
  #pragma unroll
  for (int kk = 0; kk < 8; ++kk)
    qf[kk] = *reinterpret_cast<const bf16x8*>(Qbase + (size_t)qrow * HD + kk * 16 + hi * 8);

  f32x16 accO[4];
  #pragma unroll
  for (int dt = 0; dt < 4; ++dt)
    #pragma unroll
    for (int e = 0; e < 16; ++e) accO[dt][e] = 0.f;
  float m = -3.0e38f, l = 0.f;

  // prologue: stage tile 0
  #pragma unroll
  for (int i = 0; i < 4; ++i) {
    gload_lds16(Kbase + koff[i], &Kbuf[0][(w * 256 + i * 64) * 8]);
    gload_lds16(Vbase + voff[i], &Vbuf[0][(w * 256 + i * 64) * 8]);
  }
  __syncthreads();

  for (int t = 0; t < nt; ++t) {
    const int pb = t & 1;
    if (t + 1 < nt) {
      const bf16_t* kg = Kbase + (size_t)(t + 1) * (KVB * HD);
      const bf16_t* vg = Vbase + (size_t)(t + 1) * (HD * KVB);
      #pragma unroll
      for (int i = 0; i < 4; ++i) {
        gload_lds16(kg + koff[i], &Kbuf[pb ^ 1][(w * 256 + i * 64) * 8]);
        gload_lds16(vg + voff[i], &Vbuf[pb ^ 1][(w * 256 + i * 64) * 8]);
      }
    }
    const int kv0 = t * 64;
    if (kv0 <= qmax) {
      // ---- S^T = K Q^T : 2 kv-subtiles x 8 mfma (K-dim 16 each)
      const bf16_t* kb = &Kbuf[pb][0];
      f32x16 st0, st1;
      #pragma unroll
      for (int e = 0; e < 16; ++e) { st0[e] = 0.f; st1[e] = 0.f; }
      __builtin_amdgcn_s_setprio(1);
      #pragma unroll
      for (int kk = 0; kk < 8; ++kk) {
        const int co = ((2 * kk + hi) ^ r7) * 8;
        bf16x8 k0 = *reinterpret_cast<const bf16x8*>(kb + r0 * HD + co);
        bf16x8 k1 = *reinterpret_cast<const bf16x8*>(kb + (32 + r0) * HD + co);
        st0 = __builtin_amdgcn_mfma_f32_32x32x16_bf16(k0, qf[kk], st0, 0, 0, 0);
        st1 = __builtin_amdgcn_mfma_f32_32x32x16_bf16(k1, qf[kk], st1, 0, 0, 0);
      }
      __builtin_amdgcn_s_setprio(0);

      // ---- in-register softmax (lane owns q-row r0; 32 kv vals w/ partner lane)
      float p[32];
      const bool need_mask = (kv0 + 63 > qw0);
      #pragma unroll
      for (int j = 0; j < 2; ++j)
        #pragma unroll
        for (int e = 0; e < 16; ++e) {
          float s = j ? st1[e] : st0[e];
          if (need_mask) {
            int kv = kv0 + j * 32 + (e & 3) + 8 * (e >> 2) + 4 * hi;
            s = (kv > qrow) ? -3.0e38f : s;
          }
          p[j * 16 + e] = s;
        }
      float mt[16];
      #pragma unroll
      for (int e = 0; e < 16; ++e) mt[e] = fmaxf(p[e], p[e + 16]);
      #pragma unroll
      for (int e = 0; e < 8; ++e) mt[e] = fmaxf(mt[e], mt[e + 8]);
      #pragma unroll
      for (int e = 0; e < 4; ++e) mt[e] = fmaxf(mt[e], mt[e + 4]);
      float lmx = fmaxf(fmaxf(mt[0], mt[1]), fmaxf(mt[2], mt[3]));
      float cmx = fmaxf(lmx, __shfl_xor(lmx, 32, 64));
      if (!__all(cmx <= m + 8.0f)) {        // T13 defer-max
        float mnew = fmaxf(m, cmx);
        float resc = exp2f(m - mnew);
        m = mnew;
        l *= resc;
        #pragma unroll
        for (int dt = 0; dt < 4; ++dt)
          #pragma unroll
          for (int e = 0; e < 16; ++e) accO[dt][e] *= resc;
      }
      #pragma unroll
      for (int e = 0; e < 32; ++e) p[e] = exp2f(p[e] - m);
      float sv[16];
      #pragma unroll
      for (int e = 0; e < 16; ++e) sv[e] = p[e] + p[e + 16];
      #pragma unroll
      for (int e = 0; e < 8; ++e) sv[e] += sv[e + 8];
      #pragma unroll
      for (int e = 0; e < 4; ++e) sv[e] += sv[e + 4];
      float lsum = (sv[0] + sv[1]) + (sv[2] + sv[3]);
      l += lsum + __shfl_xor(lsum, 32, 64);

      // ---- P -> bf16 B-fragments (partner exchange via shfl_xor, unambiguous)
      u32x4 pw[4];
      #pragma unroll
      for (int j = 0; j < 2; ++j) {
        const int o = j * 16;
        {
          uint32_t A = pack2(p[o + 0], p[o + 1]);
          uint32_t C = pack2(p[o + 2], p[o + 3]);
          uint32_t B = pack2(p[o + 4], p[o + 5]);
          uint32_t D = pack2(p[o + 6], p[o + 7]);
          uint32_t At = __shfl_xor(A, 32, 64), Ct = __shfl_xor(C, 32, 64);
          uint32_t Bt = __shfl_xor(B, 32, 64), Dt = __shfl_xor(D, 32, 64);
          pw[2 * j] = hi ? (u32x4){Bt, Dt, B, D} : (u32x4){A, C, At, Ct};
        }
        {
          uint32_t A = pack2(p[o + 8],  p[o + 9]);
          uint32_t C = pack2(p[o + 10], p[o + 11]);
          uint32_t B = pack2(p[o + 12], p[o + 13]);
          uint32_t D = pack2(p[o + 14], p[o + 15]);
          uint32_t At = __shfl_xor(A, 32, 64), Ct = __shfl_xor(C, 32, 64);
          uint32_t Bt = __shfl_xor(B, 32, 64), Dt = __shfl_xor(D, 32, 64);
          pw[2 * j + 1] = hi ? (u32x4){Bt, Dt, B, D} : (u32x4){A, C, At, Ct};
        }
      }

      // ---- O^T += V^T P^T : 4 d-subtiles x 4 kv-steps
      const bf16_t* vb = &Vbuf[pb][0];
      __builtin_amdgcn_s_setprio(1);
      #pragma unroll
      for (int kk = 0; kk < 4; ++kk) {
        bf16x8 pf = __builtin_bit_cast(bf16x8, pw[kk]);
        #pragma unroll
        for (int dt = 0; dt < 4; ++dt) {
          const int row = dt * 32 + r0;
          bf16x8 vf = *reinterpret_cast<const bf16x8*>(
              vb + row * KVB + (((2 * kk + hi) ^ r7) * 8));
          accO[dt] = __builtin_amdgcn_mfma_f32_32x32x16_bf16(vf, pf, accO[dt], 0, 0, 0);
        }
      }
      __builtin_amdgcn_s_setprio(0);
    }
    __syncthreads();
  }

  // ---- epilogue: lane owns q-row; float4 stores
  const float inv = 1.0f / l;
  float* orow = out + ((size_t)(b * S_LEN + qrow) * (HQ * HD)) + h * HD + hi * 4;
  #pragma unroll
  for (int dt = 0; dt < 4; ++dt)
    #pragma unroll
    for (int rg = 0; rg < 4; ++rg) {
      f32x4 v4 = { accO[dt][4 * rg + 0] * inv, accO[dt][4 * rg + 1] * inv,
                   accO[dt][4 * rg + 2] * inv, accO[dt][4 * rg + 3] * inv };
      *reinterpret_cast<f32x4*>(orow + dt * 32 + rg * 8) = v4;
    }
}

extern "C" void kernel_launch(void* const* d_in, const int* in_sizes, int n_in,
                              void* d_out, int out_size, void* d_ws, size_t ws_size,
                              hipStream_t stream) {
  const float* xq = (const float*)d_in[0];
  const float* xk = (const float*)d_in[1];
  const float* xv = (const float*)d_in[2];
  float* out = (float*)d_out;

  char* ws = (char*)d_ws;
  float2* tab = (float2*)ws;
  size_t off = (size_t)S_LEN * 64 * sizeof(float2);
  bf16_t* Qr  = (bf16_t*)(ws + off); off += (size_t)NB * HQ  * S_LEN * HD * sizeof(bf16_t);
  bf16_t* Kr  = (bf16_t*)(ws + off); off += (size_t)NB * HKV * S_LEN * HD * sizeof(bf16_t);
  bf16_t* Vtt = (bf16_t*)(ws + off);

  rope_table_kernel<<<(S_LEN * 64 + 255) / 256, 256, 0, stream>>>(tab);

  const int nrow = NB * S_LEN * (HQ + HKV);
  qk_preproc_kernel<<<nrow / 4, 256, 0, stream>>>(xq, xk, tab, Qr, Kr);

  v_preproc_kernel<<<NB * HKV * 32, 256, 0, stream>>>(xv, Vtt);

  dim3 grid(S_LEN / QBB, NB * HQ);
  attn_kernel<<<grid, 256, 0, stream>>>(Qr, Kr, Vtt, out);
}